// Round 4
// baseline (220.564 us; speedup 1.0000x reference)
//
#include <hip/hip_runtime.h>

#define B_  8
#define C_  256
#define L_  4096
#define KD_ 768   // 256 ci * 3 taps, kd = ci*3 + k

typedef __attribute__((ext_vector_type(8))) __bf16 bf16x8;
typedef __attribute__((ext_vector_type(4))) float f32x4;
typedef __attribute__((ext_vector_type(8))) unsigned short u16x8;
typedef __attribute__((ext_vector_type(4))) unsigned short u16x4;

__device__ __forceinline__ unsigned short f2bf(float f){
  union { float f; unsigned u; } v; v.f = f;
  unsigned r = v.u + 0x7fffu + ((v.u >> 16) & 1u);   // RNE
  return (unsigned short)(r >> 16);
}
__device__ __forceinline__ float bf2f(unsigned short h){
  union { unsigned u; float f; } v; v.u = ((unsigned)h) << 16;
  return v.f;
}

// Swizzled u16 index into a [128][96] u16 tile (row stride 192B).
// XOR col bits 3..4 with row bits 0..1 (stays inside each 32-col block, so
// col<96 remains valid): 16-consecutive-row ds_read_b128 -> 2-way (free).
__device__ __forceinline__ int swz96(int row, int col){
  return row * 96 + (col ^ ((row & 3) << 3));
}

// ---- prep: both weight tensors [256][768] fp32 -> bf16, natural layout ----
__global__ __launch_bounds__(256) void prep_w(const float* __restrict__ offw,
                                              const float* __restrict__ w,
                                              unsigned short* __restrict__ wO,
                                              unsigned short* __restrict__ wM){
  int i4 = blockIdx.x * 256 + threadIdx.x;   // 192 blocks * 256 * 4 = 196608
  float4 a = reinterpret_cast<const float4*>(offw)[i4];
  float4 b = reinterpret_cast<const float4*>(w)[i4];
  u16x4 ha, hb;
  ha[0]=f2bf(a.x); ha[1]=f2bf(a.y); ha[2]=f2bf(a.z); ha[3]=f2bf(a.w);
  hb[0]=f2bf(b.x); hb[1]=f2bf(b.y); hb[2]=f2bf(b.z); hb[3]=f2bf(b.w);
  reinterpret_cast<u16x4*>(wO)[i4] = ha;
  reinterpret_cast<u16x4*>(wM)[i4] = hb;
}

// ---- unified GEMM: MODE 0 = offset conv (off==0 exact), MODE 1 = deform ----
// D[m][l] = sum_kd A[m][kd] * S[l][kd], kd = ci*3+k
// A-fragments: direct global->VGPR (L2-hot 384KB, no LDS, no barrier).
// B (sampled): LDS double-buffer, gathers issued one chunk early (registers),
// ONE barrier per chunk.
template <int MODE>
__global__ __launch_bounds__(512, 4) void dconv_gemm(
    const float* __restrict__ x,
    const unsigned short* __restrict__ wT,
    const float* __restrict__ bvec,
    const unsigned short* __restrict__ off_in,
    void* __restrict__ outp){
  __shared__ __align__(16) unsigned short Bs[2][128 * 96];   // 48KB total

  // XCD swizzle: 512 blocks, 8 XCDs -> batch b pinned to one XCD (x slab 4MB = L2)
  int bid = blockIdx.x;
  int wk = (bid & 7) * 64 + (bid >> 3);
  int b  = wk >> 6;
  int yt = (wk >> 5) & 1;
  int lt = wk & 31;
  int l0 = lt * 128, m0 = yt * 128;

  int t = threadIdx.x, lane = t & 63, wid = t >> 6;
  int wm = wid >> 1, wn = wid & 1;               // wave tile: 32 m x 64 l
  const float* xb = x + (size_t)b * C_ * L_;
  const unsigned short* offp = off_in + (size_t)b * C_ * L_;
  f32x4 acc[2][4] = {};

  // sampling coords: wave = 8 rows x 8 cols per it
  int cc_b = t & 7;
  int lr_b = ((t >> 3) & 7) + wid * 8;
  constexpr int NJ = MODE ? 4 : 3;

  // A-fragment base addressing (per-lane, natural [m][768] bf16 layout)
  const unsigned short* aBase = wT + (size_t)(m0 + wm * 32 + (lane & 15)) * KD_
                                   + (lane >> 4) * 8;

  float gv[8][NJ]; float gw[8];

  // ---- prologue: gather + write chunk 0
  #pragma unroll
  for (int it = 0; it < 8; ++it){
    int cc = cc_b + 8 * (it & 3);
    int lrow = lr_b + (it >> 2) * 64;
    int c = cc, l = l0 + lrow;
    int i0; float w1;
    if (MODE){
      float off = bf2f(offp[(size_t)c * L_ + l]);
      float pos = (float)(l - 1) + off;
      float p0  = floorf(pos);
      w1 = pos - p0; i0 = (int)p0;
    } else { i0 = l - 1; w1 = 0.f; }
    const float* xr = xb + (size_t)c * L_;
    float v[NJ];
    #pragma unroll
    for (int j = 0; j < NJ; ++j){
      int ix = i0 + j;
      v[j] = (ix >= 0 && ix < L_) ? xr[ix] : 0.f;
    }
    #pragma unroll
    for (int k = 0; k < 3; ++k){
      float s = MODE ? (v[k] * (1.f - w1) + v[k + 1] * w1) : v[k];
      Bs[0][swz96(lrow, cc * 3 + k)] = f2bf(s);
    }
  }
  __syncthreads();

  // ---- main loop: one barrier per chunk
  for (int ch = 0; ch < 8; ++ch){
    int p = ch & 1;
    bool pre = (ch < 7);
    if (pre){
      int cin = (ch + 1) * 32;
      #pragma unroll
      for (int it = 0; it < 8; ++it){
        int cc = cc_b + 8 * (it & 3);
        int lrow = lr_b + (it >> 2) * 64;
        int c = cin + cc, l = l0 + lrow;
        int i0;
        if (MODE){
          float off = bf2f(offp[(size_t)c * L_ + l]);
          float pos = (float)(l - 1) + off;
          float p0  = floorf(pos);
          gw[it] = pos - p0; i0 = (int)p0;
        } else { i0 = l - 1; gw[it] = 0.f; }
        const float* xr = xb + (size_t)c * L_;
        #pragma unroll
        for (int j = 0; j < NJ; ++j){
          int ix = i0 + j;
          gv[it][j] = (ix >= 0 && ix < L_) ? xr[ix] : 0.f;
        }
      }
    }
    // MFMA on Bs[p]; A-fragments straight from global (independent of gathers)
    const unsigned short* Bp = Bs[p];
    #pragma unroll
    for (int kf = 0; kf < 3; ++kf){
      int col = kf * 32 + (lane >> 4) * 8;
      bf16x8 af[2], bfv[4];
      #pragma unroll
      for (int mi = 0; mi < 2; ++mi)
        af[mi] = __builtin_bit_cast(bf16x8,
          *reinterpret_cast<const u16x8*>(aBase + (size_t)mi * 16 * KD_ + ch * 96 + kf * 32));
      #pragma unroll
      for (int ni = 0; ni < 4; ++ni)
        bfv[ni] = __builtin_bit_cast(bf16x8,
          *reinterpret_cast<const u16x8*>(&Bp[swz96(wn * 64 + ni * 16 + (lane & 15), col)]));
      #pragma unroll
      for (int mi = 0; mi < 2; ++mi)
        #pragma unroll
        for (int ni = 0; ni < 4; ++ni)
          acc[mi][ni] = __builtin_amdgcn_mfma_f32_16x16x32_bf16(af[mi], bfv[ni], acc[mi][ni], 0, 0, 0);
    }
    if (pre){
      unsigned short* Bn = Bs[p ^ 1];
      #pragma unroll
      for (int it = 0; it < 8; ++it){
        int cc = cc_b + 8 * (it & 3);
        int lrow = lr_b + (it >> 2) * 64;
        #pragma unroll
        for (int k = 0; k < 3; ++k){
          float s = MODE ? (gv[it][k] * (1.f - gw[it]) + gv[it][k + 1] * gw[it])
                         : gv[it][k];
          Bn[swz96(lrow, cc * 3 + k)] = f2bf(s);
        }
      }
      __syncthreads();
    }
  }

  // ---- epilogue
  int rg = lane >> 4, cx = lane & 15;
  if (MODE == 0){
    unsigned short* ob = (unsigned short*)outp + (size_t)b * C_ * L_;
    #pragma unroll
    for (int mi = 0; mi < 2; ++mi)
      #pragma unroll
      for (int r = 0; r < 4; ++r){
        int c = m0 + wm * 32 + mi * 16 + rg * 4 + r;
        float bv = bvec[c];
        #pragma unroll
        for (int ni = 0; ni < 4; ++ni){
          int l = l0 + wn * 64 + ni * 16 + cx;
          ob[(size_t)c * L_ + l] = f2bf(acc[mi][ni][r] + bv);
        }
      }
  } else {
    float* ob = (float*)outp + (size_t)b * C_ * L_;
    #pragma unroll
    for (int mi = 0; mi < 2; ++mi)
      #pragma unroll
      for (int r = 0; r < 4; ++r){
        int o = m0 + wm * 32 + mi * 16 + rg * 4 + r;
        float bv = bvec[o];
        #pragma unroll
        for (int ni = 0; ni < 4; ++ni){
          int l = l0 + wn * 64 + ni * 16 + cx;
          ob[(size_t)o * L_ + l] = acc[mi][ni][r] + bv;
        }
      }
  }
}

extern "C" void kernel_launch(void* const* d_in, const int* in_sizes, int n_in,
                              void* d_out, int out_size, void* d_ws, size_t ws_size,
                              hipStream_t stream){
  (void)in_sizes; (void)n_in; (void)out_size; (void)ws_size;
  const float* x   = (const float*)d_in[0];
  const float* ow  = (const float*)d_in[1];
  const float* obv = (const float*)d_in[2];
  const float* w   = (const float*)d_in[3];
  const float* bv  = (const float*)d_in[4];
  float* out = (float*)d_out;

  unsigned short* wO     = (unsigned short*)d_ws;   // 256*768 u16 = 384KB
  unsigned short* wM     = wO + 256 * KD_;          // 384KB
  unsigned short* off_ws = wM + 256 * KD_;          // 16MB bf16 off[b][c][l]

  prep_w<<<dim3(192), dim3(256), 0, stream>>>(ow, w, wO, wM);
  dconv_gemm<0><<<dim3(512), dim3(512), 0, stream>>>(x, wO, obv, off_ws, off_ws);
  dconv_gemm<1><<<dim3(512), dim3(512), 0, stream>>>(x, wM, bv, off_ws, out);
}

// Round 5
// 205.275 us; speedup vs baseline: 1.0745x; 1.0745x over previous
//
#include <hip/hip_runtime.h>

#define B_  8
#define C_  256
#define L_  4096
#define KD_ 768   // 256 ci * 3 taps, kd = ci*3 + k

typedef __attribute__((ext_vector_type(8))) __bf16 bf16x8;
typedef __attribute__((ext_vector_type(4))) float f32x4;
typedef __attribute__((ext_vector_type(8))) unsigned short u16x8;

__device__ __forceinline__ unsigned short f2bf(float f){
  union { float f; unsigned u; } v; v.f = f;
  unsigned r = v.u + 0x7fffu + ((v.u >> 16) & 1u);   // RNE
  return (unsigned short)(r >> 16);
}
__device__ __forceinline__ float bf2f(unsigned short h){
  union { unsigned u; float f; } v; v.u = ((unsigned)h) << 16;
  return v.f;
}

// Swizzled u16 index into a [128][96] u16 tile (row stride 192B).
// XOR col bits 3..4 with row bits 2..3: stays inside each 32-col group
// (96 = 3 groups); 16-consecutive-row ds_read_b128 -> balanced 2-way (free).
__device__ __forceinline__ int swz96(int row, int col){
  return row * 96 + (col ^ (((row >> 2) & 3) << 3));
}

// async global->LDS: 24KB tile, 16B/lane, linear LDS dest (source pre-swizzled)
__device__ __forceinline__ void stage_tile24k(const unsigned short* __restrict__ g,
                                              unsigned short* l, int t){
  int wid = t >> 6, lane = t & 63;
  #pragma unroll
  for (int s = 0; s < 3; ++s){
    int seg = wid * 3 + s;                 // 24 segments of 1KB
    const char* src = (const char*)g + seg * 1024 + lane * 16;
    char* dst = (char*)l + seg * 1024;
    __builtin_amdgcn_global_load_lds(
        (const __attribute__((address_space(1))) unsigned int*)src,
        (__attribute__((address_space(3))) unsigned int*)dst, 16, 0, 0);
  }
}

// ---- prep: weights [256][768] fp32 -> bf16 swizzled compact tiles ----------
// layout: [rt(2)][ch(8)][swz96(row 128, col 96)], tile = 12288 u16 = 24KB
__global__ __launch_bounds__(256) void prep_w(const float* __restrict__ offw,
                                              const float* __restrict__ w,
                                              unsigned short* __restrict__ wO,
                                              unsigned short* __restrict__ wM){
  int idx = blockIdx.x * 256 + threadIdx.x;   // 768 blocks * 256 = 196608 exact
  int r = idx / KD_, rem = idx % KD_;
  int rt = r >> 7, row = r & 127;
  int ch = rem / 96, col = rem % 96;
  int pos = (rt * 8 + ch) * 12288 + swz96(row, col);
  wO[pos] = f2bf(offw[idx]);
  wM[pos] = f2bf(w[idx]);
}

// ---- unified GEMM (R2-main schedule): MODE 0 = off-conv (off==0 exact),
//      MODE 1 = deform conv. Per chunk: issue As stage (async gll), sample
//      Bs (long-latency gathers hide the gll), sync, MFMA, sync.
template <int MODE>
__global__ __launch_bounds__(512, 6) void dconv_gemm(
    const float* __restrict__ x,
    const unsigned short* __restrict__ wT,
    const float* __restrict__ bvec,
    const unsigned short* __restrict__ off_in,
    void* __restrict__ outp){
  __shared__ __align__(16) unsigned short As[12288];   // 24KB
  __shared__ __align__(16) unsigned short Bs[12288];   // 24KB -> 3 blocks/CU

  // XCD swizzle: 512 blocks, 8 XCDs -> batch b pinned to one XCD
  int bid = blockIdx.x;
  int wk = (bid & 7) * 64 + (bid >> 3);
  int b  = wk >> 6;
  int yt = (wk >> 5) & 1;
  int lt = wk & 31;
  int l0 = lt * 128, m0 = yt * 128;

  int t = threadIdx.x, lane = t & 63, wid = t >> 6;
  int wm = wid >> 1, wn = wid & 1;               // wave tile: 32 m x 64 l
  const float* xb = x + (size_t)b * C_ * L_;
  const unsigned short* offp = off_in + (size_t)b * C_ * L_;
  const unsigned short* wBase = wT + (size_t)yt * 8 * 12288;
  f32x4 acc[2][4] = {};

  // sampling coords: wave covers 8 rows x 8 cols per it
  int cc_b = t & 7;
  int lr_b = ((t >> 3) & 7) + wid * 8;
  constexpr int NJ = MODE ? 4 : 3;

  for (int ch = 0; ch < 8; ++ch){
    // issue next As tile first: async, drains at the barrier below,
    // latency hidden under the sampling gather chain
    stage_tile24k(wBase + (size_t)ch * 12288, As, t);
    int cin = ch * 32;
    #pragma unroll
    for (int it = 0; it < 8; ++it){
      int cc = cc_b + 8 * (it & 3);
      int lrow = lr_b + (it >> 2) * 64;
      int c = cin + cc, l = l0 + lrow;
      int i0; float w1;
      if (MODE){
        float off = bf2f(offp[(size_t)c * L_ + l]);
        float pos = (float)(l - 1) + off;
        float p0  = floorf(pos);
        w1 = pos - p0; i0 = (int)p0;
      } else { i0 = l - 1; w1 = 0.f; }
      const float* xr = xb + (size_t)c * L_;
      float v[NJ];
      #pragma unroll
      for (int j = 0; j < NJ; ++j){
        int ix = i0 + j;
        v[j] = (ix >= 0 && ix < L_) ? xr[ix] : 0.f;
      }
      #pragma unroll
      for (int k = 0; k < 3; ++k){
        float s = MODE ? (v[k] * (1.f - w1) + v[k + 1] * w1) : v[k];
        Bs[swz96(lrow, cc * 3 + k)] = f2bf(s);
      }
    }
    __syncthreads();
    // MFMA on As/Bs
    #pragma unroll
    for (int kf = 0; kf < 3; ++kf){
      int col = kf * 32 + (lane >> 4) * 8;
      bf16x8 af[2], bfv[4];
      #pragma unroll
      for (int mi = 0; mi < 2; ++mi)
        af[mi] = __builtin_bit_cast(bf16x8,
          *reinterpret_cast<const u16x8*>(&As[swz96(wm * 32 + mi * 16 + (lane & 15), col)]));
      #pragma unroll
      for (int ni = 0; ni < 4; ++ni)
        bfv[ni] = __builtin_bit_cast(bf16x8,
          *reinterpret_cast<const u16x8*>(&Bs[swz96(wn * 64 + ni * 16 + (lane & 15), col)]));
      #pragma unroll
      for (int mi = 0; mi < 2; ++mi)
        #pragma unroll
        for (int ni = 0; ni < 4; ++ni)
          acc[mi][ni] = __builtin_amdgcn_mfma_f32_16x16x32_bf16(af[mi], bfv[ni], acc[mi][ni], 0, 0, 0);
    }
    __syncthreads();
  }

  // ---- epilogue
  int rg = lane >> 4, cx = lane & 15;
  if (MODE == 0){
    unsigned short* ob = (unsigned short*)outp + (size_t)b * C_ * L_;
    #pragma unroll
    for (int mi = 0; mi < 2; ++mi)
      #pragma unroll
      for (int r = 0; r < 4; ++r){
        int c = m0 + wm * 32 + mi * 16 + rg * 4 + r;
        float bv = bvec[c];
        #pragma unroll
        for (int ni = 0; ni < 4; ++ni){
          int l = l0 + wn * 64 + ni * 16 + cx;
          ob[(size_t)c * L_ + l] = f2bf(acc[mi][ni][r] + bv);
        }
      }
  } else {
    float* ob = (float*)outp + (size_t)b * C_ * L_;
    #pragma unroll
    for (int mi = 0; mi < 2; ++mi)
      #pragma unroll
      for (int r = 0; r < 4; ++r){
        int o = m0 + wm * 32 + mi * 16 + rg * 4 + r;
        float bv = bvec[o];
        #pragma unroll
        for (int ni = 0; ni < 4; ++ni){
          int l = l0 + wn * 64 + ni * 16 + cx;
          ob[(size_t)o * L_ + l] = acc[mi][ni][r] + bv;
        }
      }
  }
}

extern "C" void kernel_launch(void* const* d_in, const int* in_sizes, int n_in,
                              void* d_out, int out_size, void* d_ws, size_t ws_size,
                              hipStream_t stream){
  (void)in_sizes; (void)n_in; (void)out_size; (void)ws_size;
  const float* x   = (const float*)d_in[0];
  const float* ow  = (const float*)d_in[1];
  const float* obv = (const float*)d_in[2];
  const float* w   = (const float*)d_in[3];
  const float* bv  = (const float*)d_in[4];
  float* out = (float*)d_out;

  unsigned short* wO     = (unsigned short*)d_ws;   // 2*8*12288 u16 = 384KB
  unsigned short* wM     = wO + 2 * 8 * 12288;      // 384KB
  unsigned short* off_ws = wM + 2 * 8 * 12288;      // 16MB bf16 off[b][c][l]

  prep_w<<<dim3(768), dim3(256), 0, stream>>>(ow, w, wO, wM);
  dconv_gemm<0><<<dim3(512), dim3(512), 0, stream>>>(x, wO, obv, off_ws, off_ws);
  dconv_gemm<1><<<dim3(512), dim3(512), 0, stream>>>(x, wM, bv, off_ws, out);
}

// Round 6
// 95.428 us; speedup vs baseline: 2.3113x; 2.1511x over previous
//
#include <hip/hip_runtime.h>

#define B_  8
#define C_  256
#define L_  4096
#define KD_ 768   // 256 ci * 3 taps, kd = ci*3 + k

typedef __attribute__((ext_vector_type(8))) __bf16 bf16x8;
typedef __attribute__((ext_vector_type(4))) float f32x4;
typedef __attribute__((ext_vector_type(8))) unsigned short u16x8;

__device__ __forceinline__ unsigned short f2bf(float f){
  union { float f; unsigned u; } v; v.f = f;
  unsigned r = v.u + 0x7fffu + ((v.u >> 16) & 1u);   // RNE
  return (unsigned short)(r >> 16);
}
__device__ __forceinline__ float bf2f(unsigned short h){
  union { unsigned u; float f; } v; v.u = ((unsigned)h) << 16;
  return v.f;
}

// Swizzled u16 index in a [rows][128] u16 tile (row stride 256B).
// XOR col bits 3..5 with row bits 0..2 (R2-proven layout).
__device__ __forceinline__ int swz(int row, int col){
  return (row << 7) + (col ^ ((row & 7) << 3));
}

// async global->LDS: 32KB tile, 16B/lane, linear LDS dest (source pre-swizzled)
__device__ __forceinline__ void stage_tile32k(const unsigned short* __restrict__ g,
                                              unsigned short* l, int t){
  int wid = t >> 6, lane = t & 63;
  #pragma unroll
  for (int s = 0; s < 4; ++s){
    int seg = wid * 4 + s;
    const char* src = (const char*)g + seg * 1024 + lane * 16;
    char* dst = (char*)l + seg * 1024;
    __builtin_amdgcn_global_load_lds(
        (const __attribute__((address_space(1))) unsigned int*)src,
        (__attribute__((address_space(3))) unsigned int*)dst, 16, 0, 0);
  }
}

// ---- prep: weights [256][768] fp32 -> bf16 swizzled tiles -------------------
// layout: [rt(2)][ch(8)][swz(row 128, col 96 pad 128)], tile 16384 u16 = 32KB
__global__ __launch_bounds__(256) void prep_w(const float* __restrict__ offw,
                                              const float* __restrict__ w,
                                              unsigned short* __restrict__ wO,
                                              unsigned short* __restrict__ wM){
  int idx = blockIdx.x * 256 + threadIdx.x;   // 768 blocks * 256 = 196608 exact
  int r = idx / KD_, rem = idx % KD_;
  int rt = r >> 7, row = r & 127;
  int ch = rem / 96, col = rem % 96;
  int pos = (rt * 8 + ch) * 16384 + swz(row, col);
  wO[pos] = f2bf(offw[idx]);
  wM[pos] = f2bf(w[idx]);
}

// ---- unified GEMM (R2 main_gemm schedule, proven 41us):
//      MODE 0 = offset conv (i0 = l-1, w1 = 0: exact im2col), bf16 out
//      MODE 1 = deform conv (lerp sample at l-1+off), fp32 out
// Per chunk: issue As stage (async gll) -> sample Bs (coalesced lane=l
// mapping: 64 consecutive l per wave) -> sync -> MFMA -> sync.
template <int MODE>
__global__ __launch_bounds__(512, 4) void dconv_gemm(
    const float* __restrict__ x,
    const unsigned short* __restrict__ wT,
    const float* __restrict__ bvec,
    const unsigned short* __restrict__ off_in,
    void* __restrict__ outp){
  __shared__ __align__(16) unsigned short As[16384];   // 32KB
  __shared__ __align__(16) unsigned short Bs[16384];   // 32KB -> 2 blocks/CU

  // XCD swizzle: 512 blocks, 8 XCDs -> batch b pinned to one XCD
  int bid = blockIdx.x;
  int wk = (bid & 7) * 64 + (bid >> 3);
  int b  = wk >> 6;
  int yt = (wk >> 5) & 1;
  int lt = wk & 31;
  int l0 = lt * 128, m0 = yt * 128;

  int t = threadIdx.x, lane = t & 63, wid = t >> 6;
  int wm = wid >> 1, wn = wid & 1;               // wave tile: 32 m x 64 l
  const float* xb = x + (size_t)b * C_ * L_;
  const unsigned short* offp = off_in + (size_t)b * C_ * L_;
  const unsigned short* wBase = wT + (size_t)yt * 8 * 16384;
  f32x4 acc[2][4] = {};
  constexpr int NJ = MODE ? 4 : 3;

  for (int ch = 0; ch < 8; ++ch){
    // async As stage issued first; drains at the barrier below, latency
    // hidden under the sampling gather chain
    stage_tile32k(wBase + (size_t)ch * 16384, As, t);
    int cin = ch * 32;
    #pragma unroll
    for (int it = 0; it < 8; ++it){
      int e = it * 512 + t;                 // 0..4095
      int lrow = e & 127, cc = e >> 7;      // lanes = consecutive l: coalesced
      int c = cin + cc;
      int l = l0 + lrow;
      int i0; float w1;
      if (MODE){
        float off = bf2f(offp[(size_t)c * L_ + l]);
        float pos = (float)(l - 1) + off;
        float p0  = floorf(pos);
        w1 = pos - p0; i0 = (int)p0;
      } else { i0 = l - 1; w1 = 0.f; }
      const float* xr = xb + (size_t)c * L_;
      float v[NJ];
      #pragma unroll
      for (int j = 0; j < NJ; ++j){
        int ix = i0 + j;
        v[j] = (ix >= 0 && ix < L_) ? xr[ix] : 0.f;
      }
      #pragma unroll
      for (int k = 0; k < 3; ++k){
        float s = MODE ? (v[k] * (1.f - w1) + v[k + 1] * w1) : v[k];
        Bs[swz(lrow, cc * 3 + k)] = f2bf(s);
      }
    }
    __syncthreads();
    // MFMA on As/Bs (cols 0..95 real, 96..127 pad never read)
    #pragma unroll
    for (int kf = 0; kf < 3; ++kf){
      int col = kf * 32 + (lane >> 4) * 8;
      bf16x8 af[2], bfv[4];
      #pragma unroll
      for (int mi = 0; mi < 2; ++mi)
        af[mi] = __builtin_bit_cast(bf16x8,
          *reinterpret_cast<const u16x8*>(&As[swz(wm * 32 + mi * 16 + (lane & 15), col)]));
      #pragma unroll
      for (int ni = 0; ni < 4; ++ni)
        bfv[ni] = __builtin_bit_cast(bf16x8,
          *reinterpret_cast<const u16x8*>(&Bs[swz(wn * 64 + ni * 16 + (lane & 15), col)]));
      #pragma unroll
      for (int mi = 0; mi < 2; ++mi)
        #pragma unroll
        for (int ni = 0; ni < 4; ++ni)
          acc[mi][ni] = __builtin_amdgcn_mfma_f32_16x16x32_bf16(af[mi], bfv[ni], acc[mi][ni], 0, 0, 0);
    }
    __syncthreads();
  }

  // ---- epilogue
  int rg = lane >> 4, cx = lane & 15;
  if (MODE == 0){
    unsigned short* ob = (unsigned short*)outp + (size_t)b * C_ * L_;
    #pragma unroll
    for (int mi = 0; mi < 2; ++mi)
      #pragma unroll
      for (int r = 0; r < 4; ++r){
        int c = m0 + wm * 32 + mi * 16 + rg * 4 + r;
        float bv = bvec[c];
        #pragma unroll
        for (int ni = 0; ni < 4; ++ni){
          int l = l0 + wn * 64 + ni * 16 + cx;
          ob[(size_t)c * L_ + l] = f2bf(acc[mi][ni][r] + bv);
        }
      }
  } else {
    float* ob = (float*)outp + (size_t)b * C_ * L_;
    #pragma unroll
    for (int mi = 0; mi < 2; ++mi)
      #pragma unroll
      for (int r = 0; r < 4; ++r){
        int o = m0 + wm * 32 + mi * 16 + rg * 4 + r;
        float bv = bvec[o];
        #pragma unroll
        for (int ni = 0; ni < 4; ++ni){
          int l = l0 + wn * 64 + ni * 16 + cx;
          ob[(size_t)o * L_ + l] = acc[mi][ni][r] + bv;
        }
      }
  }
}

extern "C" void kernel_launch(void* const* d_in, const int* in_sizes, int n_in,
                              void* d_out, int out_size, void* d_ws, size_t ws_size,
                              hipStream_t stream){
  (void)in_sizes; (void)n_in; (void)out_size; (void)ws_size;
  const float* x   = (const float*)d_in[0];
  const float* ow  = (const float*)d_in[1];
  const float* obv = (const float*)d_in[2];
  const float* w   = (const float*)d_in[3];
  const float* bv  = (const float*)d_in[4];
  float* out = (float*)d_out;

  unsigned short* wO     = (unsigned short*)d_ws;   // 2*8*16384 u16 = 512KB
  unsigned short* wM     = wO + 2 * 8 * 16384;      // 512KB
  unsigned short* off_ws = wM + 2 * 8 * 16384;      // 16MB bf16 off[b][c][l]

  prep_w<<<dim3(768), dim3(256), 0, stream>>>(ow, w, wO, wM);
  dconv_gemm<0><<<dim3(512), dim3(512), 0, stream>>>(x, wO, obv, off_ws, off_ws);
  dconv_gemm<1><<<dim3(512), dim3(512), 0, stream>>>(x, wM, bv, off_ws, out);
}

// Round 8
// 67.846 us; speedup vs baseline: 3.2509x; 1.4065x over previous
//
#include <hip/hip_runtime.h>
#include <hip/hip_bf16.h>

#define B_  8
#define C_  256
#define L_  4096
#define KD_ 768    // 256 ci * 3 taps, kd = ci*3 + k
#define XPW 4112   // padded x row: 8 | 4096 | 8

typedef __attribute__((ext_vector_type(8))) __bf16 bf16x8;
typedef __attribute__((ext_vector_type(4))) float f32x4;
typedef __attribute__((ext_vector_type(8))) unsigned short u16x8;

__device__ __forceinline__ unsigned short f2bf(float f){
  union { float f; unsigned u; } v; v.f = f;
  unsigned r = v.u + 0x7fffu + ((v.u >> 16) & 1u);   // RNE
  return (unsigned short)(r >> 16);
}
__device__ __forceinline__ float bf2f(unsigned short h){
  union { unsigned u; float f; } v; v.u = ((unsigned)h) << 16;
  return v.f;
}
// pack two fp32 -> one u32 of 2x bf16 (RNE); compiles to v_cvt_pk_bf16_f32
__device__ __forceinline__ unsigned pk2bf(float lo, float hi){
  __hip_bfloat162 h2 = __float22bfloat162_rn(make_float2(lo, hi));
  unsigned u;
  __builtin_memcpy(&u, &h2, 4);
  return u;
}

// Swizzled u16 index in a [rows][128] u16 tile (row stride 256B).
// XOR col bits 3..6 with row bits 0..3: fragment b128 reads stay 2-way (free),
// packed u32 writes at fixed col go 16 distinct banks -> 4-way (1.58x).
__device__ __forceinline__ int swz(int row, int col){
  return (row << 7) + (col ^ ((row & 15) << 3));
}

// async global->LDS: 32KB tile, 16B/lane, linear LDS dest (source pre-swizzled)
__device__ __forceinline__ void stage_tile32k(const unsigned short* __restrict__ g,
                                              unsigned short* l, int t){
  int wid = t >> 6, lane = t & 63;
  #pragma unroll
  for (int s = 0; s < 4; ++s){
    int seg = wid * 4 + s;
    const char* src = (const char*)g + seg * 1024 + lane * 16;
    char* dst = (char*)l + seg * 1024;
    __builtin_amdgcn_global_load_lds(
        (const __attribute__((address_space(1))) unsigned int*)src,
        (__attribute__((address_space(3))) unsigned int*)dst, 16, 0, 0);
  }
}

// ---- prep (fused): weight tiles + padded-x copy ------------------------------
// blocks [0,768): weights [256][768] -> bf16 swizzled tiles
//   layout [rt(2)][ch(8)][swz(row 128, col 96 pad 128)]
// blocks [768,...): xpad[b][c][8 | 4096 | 8] fp32 copy + zero pads
__global__ __launch_bounds__(256) void prep(const float* __restrict__ offw,
                                            const float* __restrict__ w,
                                            const float* __restrict__ x,
                                            unsigned short* __restrict__ wO,
                                            unsigned short* __restrict__ wM,
                                            float* __restrict__ xpad){
  int blk = blockIdx.x;
  if (blk < 768){
    int idx = blk * 256 + threadIdx.x;
    int r = idx / KD_, rem = idx % KD_;
    int rt = r >> 7, row = r & 127;
    int ch = rem / 96, col = rem % 96;
    int pos = (rt * 8 + ch) * 16384 + swz(row, col);
    wO[pos] = f2bf(offw[idx]);
    wM[pos] = f2bf(w[idx]);
  } else {
    int cb  = blk - 768;              // 0..8191
    int row = cb >> 2;                // 0..2047 (= b*256 + c)
    int seg = cb & 3;
    const float4* src = reinterpret_cast<const float4*>(x + (size_t)row * L_) + seg * 256;
    float4* dst = reinterpret_cast<float4*>(xpad + (size_t)row * XPW + 8) + seg * 256;
    dst[threadIdx.x] = src[threadIdx.x];
    if (seg == 0 && threadIdx.x < 4){
      // front pad f4[0..1], back pad f4[1026..1027]
      float4* base = reinterpret_cast<float4*>(xpad + (size_t)row * XPW);
      int j = (threadIdx.x < 2) ? threadIdx.x : (1024 + threadIdx.x);
      base[j] = float4{0.f, 0.f, 0.f, 0.f};
    }
  }
}

// ---- unified GEMM (R6 schedule): MODE 0 = off-conv (i0=l-1, w1=0, exact),
//      MODE 1 = deform. PADDED 1 = bounds-free loads from xpad (med3 clamp).
template <int MODE, int PADDED>
__global__ __launch_bounds__(512, 4) void dconv_gemm(
    const float* __restrict__ xsrc,
    const unsigned short* __restrict__ wT,
    const float* __restrict__ bvec,
    const unsigned short* __restrict__ off_in,
    void* __restrict__ outp){
  __shared__ __align__(16) unsigned short As[16384];   // 32KB
  __shared__ __align__(16) unsigned short Bs[16384];   // 32KB -> 2 blocks/CU

  // XCD swizzle: 512 blocks, 8 XCDs -> batch b pinned to one XCD
  int bid = blockIdx.x;
  int wk = (bid & 7) * 64 + (bid >> 3);
  int b  = wk >> 6;
  int yt = (wk >> 5) & 1;
  int lt = wk & 31;
  int l0 = lt * 128, m0 = yt * 128;

  int t = threadIdx.x, lane = t & 63, wid = t >> 6;
  int wm = wid >> 1, wn = wid & 1;               // wave tile: 32 m x 64 l
  const float* xb = PADDED ? xsrc + (size_t)b * C_ * XPW + 8
                           : xsrc + (size_t)b * C_ * L_;
  const unsigned short* offp = off_in + (size_t)b * C_ * L_;
  const unsigned short* wBase = wT + (size_t)yt * 8 * 16384;
  f32x4 acc[2][4] = {};

  int lrow = t & 127;          // lanes = consecutive l: coalesced off/x loads
  int l = l0 + lrow;
  int cphase = t >> 7;         // 0..3

  for (int ch = 0; ch < 8; ++ch){
    // async As stage issued first; drains at the barrier, hidden under sampling
    stage_tile32k(wBase + (size_t)ch * 16384, As, t);
    int cin = ch * 32;
    #pragma unroll
    for (int it = 0; it < 4; ++it){
      int ccp = it * 4 + cphase;                 // channel pair 0..15
      float s[6];
      #pragma unroll
      for (int u = 0; u < 2; ++u){
        int c = cin + ccp * 2 + u;
        int i0; float w1;
        if (MODE){
          float off = bf2f(offp[(size_t)c * L_ + l]);
          float pos = (float)(l - 1) + off;
          if (PADDED) pos = fminf(fmaxf(pos, -6.f), (float)(L_ + 4));  // med3
          float p0 = floorf(pos);
          w1 = pos - p0; i0 = (int)p0;
        } else { i0 = l - 1; w1 = 0.f; }
        if (PADDED){
          const float* xr = xb + (size_t)c * XPW + i0;   // pads give exact zeros
          float v0 = xr[0], v1 = xr[1], v2 = xr[2];
          if (MODE){
            float v3 = xr[3];
            float w0 = 1.f - w1;
            s[u*3+0] = v0 * w0 + v1 * w1;
            s[u*3+1] = v1 * w0 + v2 * w1;
            s[u*3+2] = v2 * w0 + v3 * w1;
          } else { s[u*3+0] = v0; s[u*3+1] = v1; s[u*3+2] = v2; }
        } else {
          const float* xr = xb + (size_t)c * L_;
          float v[4]; float w0 = 1.f - w1;
          #pragma unroll
          for (int j = 0; j < (MODE ? 4 : 3); ++j){
            int ix = i0 + j;
            v[j] = ((unsigned)ix < (unsigned)L_) ? xr[ix] : 0.f;
          }
          #pragma unroll
          for (int k = 0; k < 3; ++k)
            s[u*3+k] = MODE ? (v[k] * w0 + v[k+1] * w1) : v[k];
        }
      }
      // 3 packed u32 writes (v_cvt_pk_bf16_f32): cols 6ccp..6ccp+5
      int colb = ccp * 6;
      #pragma unroll
      for (int q = 0; q < 3; ++q){
        *reinterpret_cast<unsigned*>(&Bs[swz(lrow, colb + 2*q)]) =
            pk2bf(s[2*q], s[2*q+1]);
      }
    }
    __syncthreads();
    // MFMA on As/Bs (cols 0..95 real, 96..127 pad never read)
    #pragma unroll
    for (int kf = 0; kf < 3; ++kf){
      int col = kf * 32 + (lane >> 4) * 8;
      bf16x8 af[2], bfv[4];
      #pragma unroll
      for (int mi = 0; mi < 2; ++mi)
        af[mi] = __builtin_bit_cast(bf16x8,
          *reinterpret_cast<const u16x8*>(&As[swz(wm * 32 + mi * 16 + (lane & 15), col)]));
      #pragma unroll
      for (int ni = 0; ni < 4; ++ni)
        bfv[ni] = __builtin_bit_cast(bf16x8,
          *reinterpret_cast<const u16x8*>(&Bs[swz(wn * 64 + ni * 16 + (lane & 15), col)]));
      #pragma unroll
      for (int mi = 0; mi < 2; ++mi)
        #pragma unroll
        for (int ni = 0; ni < 4; ++ni)
          acc[mi][ni] = __builtin_amdgcn_mfma_f32_16x16x32_bf16(af[mi], bfv[ni], acc[mi][ni], 0, 0, 0);
    }
    __syncthreads();
  }

  // ---- epilogue
  int rg = lane >> 4, cx = lane & 15;
  if (MODE == 0){
    unsigned short* ob = (unsigned short*)outp + (size_t)b * C_ * L_;
    #pragma unroll
    for (int mi = 0; mi < 2; ++mi)
      #pragma unroll
      for (int r = 0; r < 4; ++r){
        int c = m0 + wm * 32 + mi * 16 + rg * 4 + r;
        float bv = bvec[c];
        #pragma unroll
        for (int ni = 0; ni < 4; ++ni){
          int ll = l0 + wn * 64 + ni * 16 + cx;
          ob[(size_t)c * L_ + ll] = f2bf(acc[mi][ni][r] + bv);
        }
      }
  } else {
    float* ob = (float*)outp + (size_t)b * C_ * L_;
    #pragma unroll
    for (int mi = 0; mi < 2; ++mi)
      #pragma unroll
      for (int r = 0; r < 4; ++r){
        int o = m0 + wm * 32 + mi * 16 + rg * 4 + r;
        float bv = bvec[o];
        #pragma unroll
        for (int ni = 0; ni < 4; ++ni){
          int ll = l0 + wn * 64 + ni * 16 + cx;
          ob[(size_t)o * L_ + ll] = acc[mi][ni][r] + bv;
        }
      }
  }
}

extern "C" void kernel_launch(void* const* d_in, const int* in_sizes, int n_in,
                              void* d_out, int out_size, void* d_ws, size_t ws_size,
                              hipStream_t stream){
  (void)in_sizes; (void)n_in; (void)out_size;
  const float* x   = (const float*)d_in[0];
  const float* ow  = (const float*)d_in[1];
  const float* obv = (const float*)d_in[2];
  const float* w   = (const float*)d_in[3];
  const float* bv  = (const float*)d_in[4];
  float* out = (float*)d_out;

  unsigned short* wO     = (unsigned short*)d_ws;   // 2*8*16384 u16 = 512KB
  unsigned short* wM     = wO + 2 * 8 * 16384;      // 512KB
  unsigned short* off_ws = wM + 2 * 8 * 16384;      // 16MB bf16 off[b][c][l]
  float* xpad = (float*)(off_ws + (size_t)B_ * C_ * L_);   // 33.7MB fp32 padded x
  size_t need = (char*)(xpad + (size_t)B_ * C_ * XPW) - (char*)d_ws;
  bool pad_ok = ws_size >= need;

  prep<<<dim3(pad_ok ? 768 + 8192 : 768), dim3(256), 0, stream>>>(
      ow, w, x, wO, wM, xpad);
  dim3 blk(512), grd(512);
  if (pad_ok){
    dconv_gemm<0,1><<<grd, blk, 0, stream>>>(xpad, wO, obv, off_ws, off_ws);
    dconv_gemm<1,1><<<grd, blk, 0, stream>>>(xpad, wM, bv, off_ws, out);
  } else {
    dconv_gemm<0,0><<<grd, blk, 0, stream>>>(x, wO, obv, off_ws, off_ws);
    dconv_gemm<1,0><<<grd, blk, 0, stream>>>(x, wM, bv, off_ws, out);
  }
}